// Round 1
// baseline (333.812 us; speedup 1.0000x reference)
//
#include <hip/hip_runtime.h>

// Sparse 2-hop GCN slice: output depends only on h2[tgt], tgt = argmax(mut_mask).
// R5: dispatch-count attack (op is dispatch-bound: ~38MB traffic ≈ 6us of BW,
// but 183us measured with 7 dispatches). 4 dispatches:
//   kinit (deg=1, cnt, tgt, is64)
//   kpassA (scan col: deg atomics for ALL edges + L1 edge list)   [kpassC folded in]
//   kpassB (scan col: S1 = dedup(l1r) in LDS, emit L2 edge list)  [slot[]/wscol removed]
//   khfused (per-slot xsum->W1->relu->a_v*h accum; last-block ticket does W2 + MLP head)
// Cross-block comms inside khfused use device-scope atomics only (G16).

#define SCAP   512      // cap on |S1|; expected ~17
#define L1CAP  512      // cap on edges into tgt; expected ~17
#define L2CAP  16384    // cap on edges into S1; expected ~300
#define MCAP   2048     // cap on edges into one slot; expected ~17
#define HID    256
#define INDIM  128
#define G4     64       // khfused grid

struct WsPtrs {
  int* cnt;                 // [0]=cntL1 [1]=ns [2]=cntL2 [3]=is64 [4]=tgt [5]=ticket
  float* deg;               // [N]
  int* s1;                  // [SCAP]
  int* l1r; float* l1w;     // edges into tgt
  int* l2r; int* l2s; float* l2w; // edges into S1
  float* h2;                // [HID] accumulator: sum_v a_v * relu(h1_v + b1)
};

// K1: deg=1.0 init + cnt init + argmax(one-hot mask) + is64 detect
__global__ void kinit(WsPtrs w, const int* eiraw, const float* mask, int N, int E) {
  int g = blockIdx.x * blockDim.x + threadIdx.x;
  int gs = gridDim.x * blockDim.x;
  for (int j = g; j < N; j += gs) {
    w.deg[j] = 1.0f;                 // self-loop weight
    if (mask[j] > 0.f) w.cnt[4] = j; // one-hot: exactly one thread fires
  }
  if (g < HID) w.h2[g] = 0.f;
  if (g < 3) w.cnt[g] = 0;
  if (g == 5) w.cnt[5] = 0;
  if (g == 3) {
    int bad = 0;
    long step = E / 20; if (step < 1) step = 1;
    #pragma unroll
    for (int j = 1; j <= 16; ++j) {     // independent loads, no break -> pipelined
      long idx = (long)j * step;
      if (idx < E) bad |= (eiraw[2 * idx + 1] != 0);  // ids < 2^31 -> hi word 0
    }
    w.cnt[3] = bad ? 0 : 1;
  }
}

// K2: scan col; deg atomics for ALL edges (replaces old passC); collect L1 edges
__global__ void kpassA(WsPtrs w, const int* eiraw, const float* ew, int E) {
  const int tgt = w.cnt[4];
  const bool is64 = w.cnt[3] != 0;
  const long long* ell = (const long long*)eiraw;
  int g = blockIdx.x * blockDim.x + threadIdx.x;
  int gs = gridDim.x * blockDim.x;
  for (long e = g; e < E; e += gs) {
    int c = is64 ? (int)ell[(long)E + e] : eiraw[(long)E + e];
    float wt = ew[e];
    atomicAdd(&w.deg[c], wt);          // avg 16 adds/address: low contention
    if (c == tgt) {
      int r = is64 ? (int)ell[e] : eiraw[e];
      int i1 = atomicAdd(&w.cnt[0], 1);
      if (i1 < L1CAP) { w.l1r[i1] = r; w.l1w[i1] = wt; }
    }
  }
  if (g == 0) {  // tgt's self loop (weight 1.0)
    int i1 = atomicAdd(&w.cnt[0], 1);
    if (i1 < L1CAP) { w.l1r[i1] = tgt; w.l1w[i1] = 1.0f; }
  }
}

// K3: each block dedups l1r -> identical S1 list in LDS; scan col; emit L2 edges
__global__ void kpassB(WsPtrs w, const int* eiraw, const float* ew, int E) {
  __shared__ int l1s[L1CAP];
  __shared__ int s1s[SCAP];
  __shared__ int nss;
  const bool is64 = w.cnt[3] != 0;
  const long long* ell = (const long long*)eiraw;
  int n1 = w.cnt[0]; if (n1 > L1CAP) n1 = L1CAP;
  for (int i = threadIdx.x; i < n1; i += blockDim.x) l1s[i] = w.l1r[i];
  __syncthreads();
  if (threadIdx.x == 0) {               // n1 ~17 -> trivial serial dedup from LDS
    int ns = 0;
    for (int i = 0; i < n1; ++i) {
      int v = l1s[i]; bool seen = false;
      for (int j = 0; j < ns; ++j) if (s1s[j] == v) { seen = true; break; }
      if (!seen && ns < SCAP) s1s[ns++] = v;
    }
    nss = ns;
  }
  __syncthreads();
  int ns = nss;
  if (blockIdx.x == 0) {                // publish for khfused
    for (int j = threadIdx.x; j < ns; j += blockDim.x) w.s1[j] = s1s[j];
    if (threadIdx.x == 0) w.cnt[1] = ns;
  }
  int g = blockIdx.x * blockDim.x + threadIdx.x;
  int gs = gridDim.x * blockDim.x;
  for (long e = g; e < E; e += gs) {
    int c = is64 ? (int)ell[(long)E + e] : eiraw[(long)E + e];
    int s = -1;
    for (int j = 0; j < ns; ++j) if (s1s[j] == c) { s = j; break; }  // LDS broadcast
    if (s >= 0) {
      int r = is64 ? (int)ell[e] : eiraw[e];
      int idx = atomicAdd(&w.cnt[2], 1);
      if (idx < L2CAP) { w.l2r[idx] = r; w.l2s[idx] = s; w.l2w[idx] = ew[e]; }
    }
  }
}

// K4: one block per S1 slot:
//   xsum = x[v]/deg[v] + sum_{l2 e->v} norm_e * x[r_e]        (linearity: 1 W1 matvec/slot)
//   h1_v = relu(xsum @ W1 + b1);  a_v = dinv[v]*(sum l1 wt)*dinv[tgt]
//   h2 += a_v * h1_v   (global atomics)
// last-ticket block:  feat0 = relu(h2 @ W2 + b2)*mask[tgt];  then MLP head.
__global__ void __launch_bounds__(256) khfused(
    WsPtrs w, const float* x, const float* W1, const float* b1,
    const float* W2, const float* b2, const float* mask,
    const int* wtI_, const int* mutI_,
    const float* aa, const float* pemb,
    const float* Wh1, const float* bh1,
    const float* Wh2, const float* bh2,
    const float* Wh3, const float* bh3,
    float* out) {
  __shared__ int   l1rS[L1CAP];
  __shared__ float l1wS[L1CAP];
  __shared__ int   mr[MCAP];
  __shared__ float mn[MCAP];
  __shared__ int   mcnt;
  __shared__ float xsum[INDIM];
  __shared__ float hsL[HID];
  __shared__ float feat[480];
  __shared__ float f1[512];
  __shared__ float pp[256];
  __shared__ int   lastFlag;

  int tid = threadIdx.x;
  int tgt = w.cnt[4];
  int ns = w.cnt[1]; if (ns > SCAP) ns = SCAP;
  int n1 = w.cnt[0]; if (n1 > L1CAP) n1 = L1CAP;
  int n2 = w.cnt[2]; if (n2 > L2CAP) n2 = L2CAP;
  float dti = rsqrtf(w.deg[tgt]);

  if (blockIdx.x < ns) {
    for (int i = tid; i < n1; i += 256) { l1rS[i] = w.l1r[i]; l1wS[i] = w.l1w[i]; }
    for (int s = blockIdx.x; s < ns; s += gridDim.x) {
      int v = w.s1[s];
      float dv = w.deg[v];
      float dvi = rsqrtf(dv);
      if (tid == 0) mcnt = 0;
      __syncthreads();                        // covers l1 preload + mcnt reset
      // parallel compaction of this slot's edges (+ per-edge norm, deg gathers)
      for (int i = tid; i < n2; i += 256) {
        if (w.l2s[i] == s) {
          int p = atomicAdd(&mcnt, 1);
          if (p < MCAP) {
            int r = w.l2r[i];
            mr[p] = r;
            mn[p] = rsqrtf(w.deg[r]) * w.l2w[i] * dvi;
          }
        }
      }
      __syncthreads();
      int m = mcnt; if (m > MCAP) m = MCAP;
      if (tid < INDIM) {
        float xacc = x[(long)v * INDIM + tid] / dv;   // self loop: dvi*1*dvi
        for (int p = 0; p < m; ++p)
          xacc += mn[p] * x[(long)mr[p] * INDIM + tid];
        xsum[tid] = xacc;
      }
      __syncthreads();
      float h = b1[tid];
      #pragma unroll 8
      for (int k = 0; k < INDIM; ++k) h += xsum[k] * W1[k * HID + tid];
      h = fmaxf(h, 0.f);
      float wsum = 0.f;                         // sum of l1 weights with row==v
      for (int i = 0; i < n1; ++i) if (l1rS[i] == v) wsum += l1wS[i];
      float av = dvi * wsum * dti;
      atomicAdd(&w.h2[tid], av * h);            // device-scope
      __syncthreads();                          // protect xsum/mr/mn for next slot
    }
  }

  __threadfence();
  if (tid == 0) {
    int t = __hip_atomic_fetch_add(&w.cnt[5], 1, __ATOMIC_ACQ_REL,
                                   __HIP_MEMORY_SCOPE_AGENT);
    lastFlag = (t == (int)gridDim.x - 1);
  }
  __syncthreads();
  if (!lastFlag) return;

  // ---- last block: single W2 matvec + MLP head (256 threads) ----
  hsL[tid] = __hip_atomic_load(&w.h2[tid], __ATOMIC_RELAXED,
                               __HIP_MEMORY_SCOPE_AGENT);
  __syncthreads();
  float y = b2[tid];
  #pragma unroll 8
  for (int k = 0; k < HID; ++k) y += hsL[k] * W2[k * HID + tid];
  feat[tid] = fmaxf(y, 0.f) * mask[tgt];
  int wtI = wtI_[0], mutI = mutI_[0];   // small non-negative; low word ok i32/i64
  if (tid < 64) {
    float a = aa[wtI * 64 + tid];
    float b = aa[mutI * 64 + tid];
    feat[256 + tid] = a; feat[320 + tid] = b; feat[384 + tid] = b - a;
  }
  int pos = tgt; if (pos > 511) pos = 511; if (pos < 0) pos = 0;
  if (tid < 32) feat[448 + tid] = pemb[pos * 32 + tid];
  __syncthreads();
  // layer 1: 512 outputs, 2 per thread, K=480
  float v0 = bh1[tid], v1 = bh1[tid + 256];
  for (int k = 0; k < 480; ++k) {
    float f = feat[k];
    v0 += f * Wh1[k * 512 + tid];
    v1 += f * Wh1[k * 512 + tid + 256];
  }
  f1[tid] = fmaxf(v0, 0.f); f1[tid + 256] = fmaxf(v1, 0.f);
  __syncthreads();
  // layer 2: 128 outputs, K=512 split in 2
  {
    int o = tid & 127, half = tid >> 7;
    float vv = 0.f;
    int k0 = half * 256;
    for (int k = k0; k < k0 + 256; ++k) vv += f1[k] * Wh2[k * 128 + o];
    pp[tid] = vv;
  }
  __syncthreads();
  if (tid < 128) pp[tid] = fmaxf(pp[tid] + pp[tid + 128] + bh2[tid], 0.f) * Wh3[tid];
  __syncthreads();
  if (tid == 0) {
    float sacc = bh3[0];
    for (int k = 0; k < 128; ++k) sacc += pp[k];
    out[0] = sacc;
  }
}

extern "C" void kernel_launch(void* const* d_in, const int* in_sizes, int n_in,
                              void* d_out, int out_size, void* d_ws, size_t ws_size,
                              hipStream_t stream) {
  const float* x    = (const float*)d_in[0];
  const int*   ei   = (const int*)d_in[1];
  const float* ew   = (const float*)d_in[2];
  const float* mask = (const float*)d_in[3];
  const int*   wtI  = (const int*)d_in[4];
  const int*   mutI = (const int*)d_in[5];
  const float* W1   = (const float*)d_in[6];
  const float* b1   = (const float*)d_in[7];
  const float* W2   = (const float*)d_in[8];
  const float* b2   = (const float*)d_in[9];
  const float* aa   = (const float*)d_in[10];
  const float* pemb = (const float*)d_in[11];
  const float* Wh1  = (const float*)d_in[12];
  const float* bh1  = (const float*)d_in[13];
  const float* Wh2  = (const float*)d_in[14];
  const float* bh2  = (const float*)d_in[15];
  const float* Wh3  = (const float*)d_in[16];
  const float* bh3  = (const float*)d_in[17];
  float* out = (float*)d_out;
  const int N = in_sizes[3];   // mut_mask length
  const int E = in_sizes[2];   // edge_weight length

  char* q = (char*)d_ws;
  auto take = [&](size_t bytes) -> char* {
    char* r = q; q += (bytes + 255) & ~(size_t)255; return r;
  };
  WsPtrs w;
  w.cnt = (int*)take(64);
  w.deg = (float*)take((size_t)N * 4);
  w.s1  = (int*)take(SCAP * 4);
  w.l1r = (int*)take(L1CAP * 4);
  w.l1w = (float*)take(L1CAP * 4);
  w.l2r = (int*)take(L2CAP * 4);
  w.l2s = (int*)take(L2CAP * 4);
  w.l2w = (float*)take(L2CAP * 4);
  w.h2  = (float*)take(HID * 4);

  kinit   <<<512, 256, 0, stream>>>(w, ei, mask, N, E);
  kpassA  <<<2048, 256, 0, stream>>>(w, ei, ew, E);
  kpassB  <<<1024, 256, 0, stream>>>(w, ei, ew, E);
  khfused <<<G4, 256, 0, stream>>>(w, x, W1, b1, W2, b2, mask, wtI, mutI,
                                   aa, pemb, Wh1, bh1, Wh2, bh2, Wh3, bh3, out);
}

// Round 2
// 241.139 us; speedup vs baseline: 1.3843x; 1.3843x over previous
//
#include <hip/hip_runtime.h>

// Sparse 2-hop GCN slice: output depends only on h2[tgt], tgt = argmax(mut_mask).
// R6: R4's proven scan pipeline (no full-E atomics, no device fences) + single-block
// fused tail. 5 dispatches:
//   kinit  (slot=-1, cnt, tgt, is64)
//   kpassA (scan int64/32 col; emit int32 wscol; L1 edges; build S1 via slot CAS)
//   kpassB (int4 scan wscol; L2 edges into S1; mark rows deg-needed; S1 self loops)
//   kpassC (deg atomics for marked nodes only, ~5K atomics)
//   kfinal (1 block x 1024 thr: per-slot xsum in LDS -> one W1 matvec/slot ->
//           h2 accum in regs -> single W2 matvec -> MLP head). No cross-block comms.

#define SCAP   512      // cap on |S1|; expected ~17
#define L1CAP  512      // cap on edges into tgt; expected ~17
#define L2CAP  16384    // cap on edges into S1; expected ~300
#define HID    256
#define INDIM  128
#define MAXS   64       // slots per kfinal chunk (LDS xsum tile)

struct WsPtrs {
  int* cnt;                 // [0]=cntL1 [1]=ns [2]=cntL2 [3]=is64 [4]=tgt
  float* deg;               // [N] lazily initialized
  int* slot;                // [N] -1 unknown, >=0 S1 slot, -2 transient, -3 deg-needed
  int* s1;                  // [SCAP]
  int* l1r; float* l1w;     // edges into tgt
  int* l2r; int* l2s; float* l2w; // edges into S1
  int* wscol;               // [E] col as int32
};

// K1: init slot + cnt + argmax(one-hot mask) + is64 detect
__global__ void kinit(WsPtrs w, const int* eiraw, const float* mask, int N, int E) {
  int g = blockIdx.x * blockDim.x + threadIdx.x;
  int gs = gridDim.x * blockDim.x;
  for (int j = g; j < N; j += gs) {
    w.slot[j] = -1;
    if (mask[j] > 0.f) w.cnt[4] = j;  // one-hot: exactly one thread fires
  }
  if (g < 3) w.cnt[g] = 0;
  if (g == 3) {
    int bad = 0;
    long step = E / 20; if (step < 1) step = 1;
    #pragma unroll
    for (int j = 1; j <= 16; ++j) {   // independent loads, pipelined
      long idx = (long)j * step;
      if (idx < E) bad |= (eiraw[2 * idx + 1] != 0);  // ids < 2^31 -> hi word 0
    }
    w.cnt[3] = bad ? 0 : 1;
  }
}

__device__ __forceinline__ void reg_s1(WsPtrs& w, int r) {
  int old = atomicCAS(&w.slot[r], -1, -2);
  if (old == -1) {
    w.deg[r] = 1.0f;                       // lazy init, self-loop weight
    int idx = atomicAdd(&w.cnt[1], 1);
    if (idx < SCAP) { w.s1[idx] = r; w.slot[r] = idx; }
    else            { w.slot[r] = -3; }
  }
}

// K2: scan int64/int32 col; emit int32 wscol; collect edges into tgt; build S1
__global__ void kpassA(WsPtrs w, const int* eiraw, const float* ew, int E) {
  const int tgt = w.cnt[4];
  const bool is64 = w.cnt[3] != 0;
  const long long* ell = (const long long*)eiraw;
  int g = blockIdx.x * blockDim.x + threadIdx.x;
  int gs = gridDim.x * blockDim.x;
  for (long e = g; e < E; e += gs) {
    int c = is64 ? (int)ell[(long)E + e] : eiraw[(long)E + e];
    w.wscol[e] = c;
    if (c == tgt) {
      int r = is64 ? (int)ell[e] : eiraw[e];
      int i1 = atomicAdd(&w.cnt[0], 1);
      if (i1 < L1CAP) { w.l1r[i1] = r; w.l1w[i1] = ew[e]; }
      reg_s1(w, r);
    }
  }
  if (g == 0) {  // tgt's self loop (weight 1.0)
    int i1 = atomicAdd(&w.cnt[0], 1);
    if (i1 < L1CAP) { w.l1r[i1] = tgt; w.l1w[i1] = 1.0f; }
    reg_s1(w, tgt);
  }
}

// K3: scan wscol (int4); collect edges into S1; mark rows deg-needed
__global__ void kpassB(WsPtrs w, const int* eiraw, const float* ew, int E) {
  const bool is64 = w.cnt[3] != 0;
  const long long* ell = (const long long*)eiraw;
  int g = blockIdx.x * blockDim.x + threadIdx.x;
  int gs = gridDim.x * blockDim.x;
  int ns = w.cnt[1]; if (ns > SCAP) ns = SCAP;
  for (int j = g; j < ns; j += gs) {   // S1 self loops
    int idx = atomicAdd(&w.cnt[2], 1);
    if (idx < L2CAP) { w.l2r[idx] = w.s1[j]; w.l2s[idx] = j; w.l2w[idx] = 1.0f; }
  }
  const int4* c4 = (const int4*)w.wscol;
  int nv = E >> 2;
  for (int j = g; j < nv; j += gs) {
    int4 v = c4[j];
    #pragma unroll
    for (int t = 0; t < 4; ++t) {
      int c = (t == 0) ? v.x : (t == 1) ? v.y : (t == 2) ? v.z : v.w;
      int s = w.slot[c];
      if (s >= 0) {
        long e = 4L * j + t;
        int r = is64 ? (int)ell[e] : eiraw[e];
        int idx = atomicAdd(&w.cnt[2], 1);
        if (idx < L2CAP) { w.l2r[idx] = r; w.l2s[idx] = s; w.l2w[idx] = ew[e]; }
        int old = atomicCAS(&w.slot[r], -1, -3);
        if (old == -1) w.deg[r] = 1.0f;
      }
    }
  }
  for (long e = 4L * nv + g; e < E; e += gs) {
    int c = w.wscol[e];
    int s = w.slot[c];
    if (s >= 0) {
      int r = is64 ? (int)ell[e] : eiraw[e];
      int idx = atomicAdd(&w.cnt[2], 1);
      if (idx < L2CAP) { w.l2r[idx] = r; w.l2s[idx] = s; w.l2w[idx] = ew[e]; }
      int old = atomicCAS(&w.slot[r], -1, -3);
      if (old == -1) w.deg[r] = 1.0f;
    }
  }
}

// K4: deg accumulation for marked nodes only (~5K atomics)
__global__ void kpassC(WsPtrs w, const float* ew, int E) {
  int g = blockIdx.x * blockDim.x + threadIdx.x;
  int gs = gridDim.x * blockDim.x;
  const int4* c4 = (const int4*)w.wscol;
  int nv = E >> 2;
  for (int j = g; j < nv; j += gs) {
    int4 v = c4[j];
    #pragma unroll
    for (int t = 0; t < 4; ++t) {
      int c = (t == 0) ? v.x : (t == 1) ? v.y : (t == 2) ? v.z : v.w;
      if (w.slot[c] != -1) atomicAdd(&w.deg[c], ew[4L * j + t]);
    }
  }
  for (long e = 4L * nv + g; e < E; e += gs) {
    int c = w.wscol[e];
    if (w.slot[c] != -1) atomicAdd(&w.deg[c], ew[e]);
  }
}

// K5: single block, 1024 threads. Per-slot xsum (LDS) -> W1 matvec -> a_v*relu accum
// in regs -> reduce -> W2 matvec -> MLP head. L2 self-loops already in l2 list.
__global__ void __launch_bounds__(1024) kfinal(
    WsPtrs w, const float* x, const float* W1, const float* b1,
    const float* W2, const float* b2, const float* mask,
    const int* wtI_, const int* mutI_,
    const float* aa, const float* pemb,
    const float* Wh1, const float* bh1,
    const float* Wh2, const float* bh2,
    const float* Wh3, const float* bh3,
    float* out) {
  __shared__ float xsumS[MAXS * INDIM];   // 32 KB
  __shared__ int   l1rS[L1CAP];
  __shared__ float l1wS[L1CAP];
  __shared__ float pp[1024];
  __shared__ float h2L[HID];
  __shared__ float feat[480];
  __shared__ float f1[512];

  int tid = threadIdx.x;
  int tgt = w.cnt[4];
  int ns = w.cnt[1]; if (ns > SCAP) ns = SCAP;
  int n1 = w.cnt[0]; if (n1 > L1CAP) n1 = L1CAP;
  int n2 = w.cnt[2]; if (n2 > L2CAP) n2 = L2CAP;
  float dti = rsqrtf(w.deg[tgt]);
  for (int i = tid; i < n1; i += 1024) { l1rS[i] = w.l1r[i]; l1wS[i] = w.l1w[i]; }

  int o = tid & 255, sg = tid >> 8;       // phase-2/3 mapping: 4 groups x 256 outputs
  int lane = tid & 127, g8 = tid >> 7;    // phase-1 mapping: 8 groups x 128 lanes
  float hacc = 0.f;                       // this thread's partial of h2[o]
  for (int cb = 0; cb < ns; cb += MAXS) {
    int ce = ns - cb; if (ce > MAXS) ce = MAXS;
    for (int j = tid; j < MAXS * INDIM; j += 1024) xsumS[j] = 0.f;
    __syncthreads();                      // also covers l1 preload (first iter)
    for (int i = g8; i < n2; i += 8) {    // edge-parallel gather
      int s = w.l2s[i] - cb;
      if (s >= 0 && s < ce) {
        int r = w.l2r[i];
        float nrm = rsqrtf(w.deg[r]) * w.l2w[i] * rsqrtf(w.deg[w.s1[s + cb]]);
        atomicAdd(&xsumS[s * INDIM + lane], nrm * x[(long)r * INDIM + lane]);
      }
    }
    __syncthreads();
    for (int s = cb + sg; s < cb + ce; s += 4) {   // slot-parallel W1 matvec
      int v = w.s1[s];
      float dvi = rsqrtf(w.deg[v]);
      const float* xs = &xsumS[(s - cb) * INDIM];
      float h = b1[o];
      #pragma unroll 8
      for (int k = 0; k < INDIM; ++k) h += xs[k] * W1[k * HID + o];
      float wsum = 0.f;                   // sum of l1 weights with row==v
      for (int i = 0; i < n1; ++i) if (l1rS[i] == v) wsum += l1wS[i];
      hacc += dvi * wsum * dti * fmaxf(h, 0.f);
    }
    __syncthreads();                      // protect xsumS for next chunk
  }
  pp[tid] = hacc;
  __syncthreads();
  if (tid < HID) h2L[tid] = pp[tid] + pp[tid + 256] + pp[tid + 512] + pp[tid + 768];
  __syncthreads();
  // conv2: feat[0:256] = relu(h2L @ W2 + b2) * mask[tgt]; split-K 4x64, coalesced
  {
    float v = 0.f;
    int k0 = sg * 64;
    #pragma unroll 8
    for (int k = k0; k < k0 + 64; ++k) v += h2L[k] * W2[k * HID + o];
    pp[tid] = v;
  }
  __syncthreads();
  float maskv = mask[tgt];
  if (tid < HID)
    feat[tid] = fmaxf(pp[tid] + pp[tid + 256] + pp[tid + 512] + pp[tid + 768]
                      + b2[tid], 0.f) * maskv;
  int wtI = wtI_[0], mutI = mutI_[0];     // small non-negative; low word ok i32/i64
  if (tid < 64) {
    float a = aa[wtI * 64 + tid];
    float b = aa[mutI * 64 + tid];
    feat[256 + tid] = a; feat[320 + tid] = b; feat[384 + tid] = b - a;
  }
  int pos = tgt; if (pos > 511) pos = 511;
  if (tid < 32) feat[448 + tid] = pemb[pos * 32 + tid];
  __syncthreads();
  // head layer 1: 512 outputs, K=480 split in 2
  {
    int oo = tid & 511, half = tid >> 9;
    int k0 = half * 240;
    float v = 0.f;
    for (int k = k0; k < k0 + 240; ++k) v += feat[k] * Wh1[k * 512 + oo];
    pp[tid] = v;
  }
  __syncthreads();
  if (tid < 512) f1[tid] = fmaxf(pp[tid] + pp[tid + 512] + bh1[tid], 0.f);
  __syncthreads();
  // head layer 2: 128 outputs, K=512 split in 8
  {
    int oo = tid & 127, part = tid >> 7;
    int k0 = part * 64;
    float v = 0.f;
    #pragma unroll 8
    for (int k = k0; k < k0 + 64; ++k) v += f1[k] * Wh2[k * 128 + oo];
    pp[tid] = v;
  }
  __syncthreads();
  if (tid < 128) {
    float v = bh2[tid];
    #pragma unroll
    for (int j = 0; j < 8; ++j) v += pp[j * 128 + tid];
    h2L[tid] = fmaxf(v, 0.f) * Wh3[tid];
  }
  __syncthreads();
  if (tid == 0) {
    float s = bh3[0];
    for (int k = 0; k < 128; ++k) s += h2L[k];
    out[0] = s;
  }
}

extern "C" void kernel_launch(void* const* d_in, const int* in_sizes, int n_in,
                              void* d_out, int out_size, void* d_ws, size_t ws_size,
                              hipStream_t stream) {
  const float* x    = (const float*)d_in[0];
  const int*   ei   = (const int*)d_in[1];
  const float* ew   = (const float*)d_in[2];
  const float* mask = (const float*)d_in[3];
  const int*   wtI  = (const int*)d_in[4];
  const int*   mutI = (const int*)d_in[5];
  const float* W1   = (const float*)d_in[6];
  const float* b1   = (const float*)d_in[7];
  const float* W2   = (const float*)d_in[8];
  const float* b2   = (const float*)d_in[9];
  const float* aa   = (const float*)d_in[10];
  const float* pemb = (const float*)d_in[11];
  const float* Wh1  = (const float*)d_in[12];
  const float* bh1  = (const float*)d_in[13];
  const float* Wh2  = (const float*)d_in[14];
  const float* bh2  = (const float*)d_in[15];
  const float* Wh3  = (const float*)d_in[16];
  const float* bh3  = (const float*)d_in[17];
  float* out = (float*)d_out;
  const int N = in_sizes[3];   // mut_mask length
  const int E = in_sizes[2];   // edge_weight length

  char* q = (char*)d_ws;
  auto take = [&](size_t bytes) -> char* {
    char* r = q; q += (bytes + 255) & ~(size_t)255; return r;
  };
  WsPtrs w;
  w.cnt   = (int*)take(64);
  w.deg   = (float*)take((size_t)N * 4);
  w.slot  = (int*)take((size_t)N * 4);
  w.s1    = (int*)take(SCAP * 4);
  w.l1r   = (int*)take(L1CAP * 4);
  w.l1w   = (float*)take(L1CAP * 4);
  w.l2r   = (int*)take(L2CAP * 4);
  w.l2s   = (int*)take(L2CAP * 4);
  w.l2w   = (float*)take(L2CAP * 4);
  w.wscol = (int*)take((size_t)E * 4);

  kinit  <<<512, 256, 0, stream>>>(w, ei, mask, N, E);
  kpassA <<<2048, 256, 0, stream>>>(w, ei, ew, E);
  kpassB <<<1024, 256, 0, stream>>>(w, ei, ew, E);
  kpassC <<<1024, 256, 0, stream>>>(w, ew, E);
  kfinal <<<1, 1024, 0, stream>>>(w, x, W1, b1, W2, b2, mask, wtI, mutI,
                                  aa, pemb, Wh1, bh1, Wh2, bh2, Wh3, bh3, out);
}

// Round 3
// 196.755 us; speedup vs baseline: 1.6966x; 1.2256x over previous
//
#include <hip/hip_runtime.h>

// Sparse 2-hop GCN slice: output depends only on h2[tgt], tgt = argmax(mut_mask).
// R7: proven 4-scan pipeline + parallel tail. 5 dispatches:
//   kinit  (slot=-1, cnt, tgt, is64, zero h2/f2pre/join counters)
//   kpassA (scan col -> wscol + L1 + S1; 8 EXTRA blocks precompute C[512] =
//           Wh1[256:480]^T feat_aa_pe concurrently -- removes 459KB from tail)
//   kpassB (int4 scan wscol; L2 edges into S1; mark rows deg-needed)
//   kpassC (deg atomics for marked nodes only)
//   ktail  (32 blocks, 3 device-scope spin-joins; every weight stream multi-CU:
//           stage0 slots->h2 | A: z=relu(W2^T h2+b2) | B: f1 slices + f2 atomics | C: out)

#define SCAP   512      // cap on |S1|; expected ~17
#define L1CAP  512      // cap on edges into tgt; expected ~17
#define L2CAP  16384    // cap on edges into S1; expected ~300
#define HID    256
#define INDIM  128
#define NSCAN  2048     // scanning blocks in kpassA
#define NTB    32       // ktail grid (all co-resident: 32 << 256 CUs)

struct WsPtrs {
  int* cnt;    // [0]=cntL1 [1]=ns [2]=cntL2 [3]=is64 [4]=tgt [8][9][10]=join counters
  float* deg;  // [N] lazily initialized
  int* slot;   // [N] -1 unknown, >=0 S1 slot, -2 transient, -3 deg-needed
  int* s1;     // [SCAP]
  int* l1r; float* l1w;            // edges into tgt
  int* l2r; int* l2s; float* l2w;  // edges into S1
  int* wscol;  // [E] col as int32
  float* h2;   // [HID]  sum_v a_v * relu(h1_v + b1)
  float* C;    // [512]  precomputed aa/pos part of head layer 1
  float* z;    // [256]  relu(h2 @ W2 + b2) * mask[tgt]
  float* f2pre;// [128]  pre-activation of head layer 2
};

// K1: init slot + cnt + argmax(one-hot mask) + is64 detect + zero accumulators
__global__ void kinit(WsPtrs w, const int* eiraw, const float* mask, int N, int E) {
  int g = blockIdx.x * blockDim.x + threadIdx.x;
  int gs = gridDim.x * blockDim.x;
  for (int j = g; j < N; j += gs) {
    w.slot[j] = -1;
    if (mask[j] > 0.f) w.cnt[4] = j;  // one-hot: exactly one thread fires
  }
  if (g < HID) w.h2[g] = 0.f;
  if (g < 128) w.f2pre[g] = 0.f;
  if (g < 3) w.cnt[g] = 0;
  if (g >= 8 && g < 11) w.cnt[g] = 0;
  if (g == 3) {
    int bad = 0;
    long step = E / 20; if (step < 1) step = 1;
    #pragma unroll
    for (int j = 1; j <= 16; ++j) {   // independent loads, pipelined
      long idx = (long)j * step;
      if (idx < E) bad |= (eiraw[2 * idx + 1] != 0);  // ids < 2^31 -> hi word 0
    }
    w.cnt[3] = bad ? 0 : 1;
  }
}

__device__ __forceinline__ void reg_s1(WsPtrs& w, int r) {
  int old = atomicCAS(&w.slot[r], -1, -2);
  if (old == -1) {
    w.deg[r] = 1.0f;                       // lazy init, self-loop weight
    int idx = atomicAdd(&w.cnt[1], 1);
    if (idx < SCAP) { w.s1[idx] = r; w.slot[r] = idx; }
    else            { w.slot[r] = -3; }
  }
}

// K2: scan int64/int32 col; emit int32 wscol; L1 edges; build S1.
// Blocks >= NSCAN: precompute C[512] (aa/pos half of head layer 1) -- concurrent.
__global__ void kpassA(WsPtrs w, const int* eiraw, const float* ew,
                       const int* wtI_, const int* mutI_,
                       const float* aa, const float* pemb, const float* Wh1, int E) {
  if (blockIdx.x >= NSCAN) {
    __shared__ float fe[224];
    __shared__ float red[256];
    int b8 = blockIdx.x - NSCAN;          // 0..7, 64 outputs each
    int t = threadIdx.x;
    int wtI = wtI_[0], mutI = mutI_[0];   // small non-negative; low word ok i32/i64
    if (t < 64) {
      float a = aa[wtI * 64 + t], b = aa[mutI * 64 + t];
      fe[t] = a; fe[64 + t] = b; fe[128 + t] = b - a;
    }
    int tgt = w.cnt[4];
    int pos = tgt > 511 ? 511 : tgt;
    if (t < 32) fe[192 + t] = pemb[pos * 32 + t];
    __syncthreads();
    int o = b8 * 64 + (t & 63), js = t >> 6;  // 4 j-slices x 56
    float v = 0.f;
    for (int j = js * 56; j < js * 56 + 56; ++j)
      v += fe[j] * Wh1[(256 + j) * 512 + o];
    red[t] = v;
    __syncthreads();
    if (t < 64) w.C[b8 * 64 + t] = red[t] + red[64 + t] + red[128 + t] + red[192 + t];
    return;
  }
  const int tgt = w.cnt[4];
  const bool is64 = w.cnt[3] != 0;
  const long long* ell = (const long long*)eiraw;
  int g = blockIdx.x * blockDim.x + threadIdx.x;
  int gs = NSCAN * blockDim.x;
  for (long e = g; e < E; e += gs) {
    int c = is64 ? (int)ell[(long)E + e] : eiraw[(long)E + e];
    w.wscol[e] = c;
    if (c == tgt) {
      int r = is64 ? (int)ell[e] : eiraw[e];
      int i1 = atomicAdd(&w.cnt[0], 1);
      if (i1 < L1CAP) { w.l1r[i1] = r; w.l1w[i1] = ew[e]; }
      reg_s1(w, r);
    }
  }
  if (g == 0) {  // tgt's self loop (weight 1.0)
    int i1 = atomicAdd(&w.cnt[0], 1);
    if (i1 < L1CAP) { w.l1r[i1] = tgt; w.l1w[i1] = 1.0f; }
    reg_s1(w, tgt);
  }
}

// K3: scan wscol (int4); collect edges into S1; mark rows deg-needed
__global__ void kpassB(WsPtrs w, const int* eiraw, const float* ew, int E) {
  const bool is64 = w.cnt[3] != 0;
  const long long* ell = (const long long*)eiraw;
  int g = blockIdx.x * blockDim.x + threadIdx.x;
  int gs = gridDim.x * blockDim.x;
  int ns = w.cnt[1]; if (ns > SCAP) ns = SCAP;
  for (int j = g; j < ns; j += gs) {   // S1 self loops
    int idx = atomicAdd(&w.cnt[2], 1);
    if (idx < L2CAP) { w.l2r[idx] = w.s1[j]; w.l2s[idx] = j; w.l2w[idx] = 1.0f; }
  }
  const int4* c4 = (const int4*)w.wscol;
  int nv = E >> 2;
  for (int j = g; j < nv; j += gs) {
    int4 v = c4[j];
    #pragma unroll
    for (int t = 0; t < 4; ++t) {
      int c = (t == 0) ? v.x : (t == 1) ? v.y : (t == 2) ? v.z : v.w;
      int s = w.slot[c];
      if (s >= 0) {
        long e = 4L * j + t;
        int r = is64 ? (int)ell[e] : eiraw[e];
        int idx = atomicAdd(&w.cnt[2], 1);
        if (idx < L2CAP) { w.l2r[idx] = r; w.l2s[idx] = s; w.l2w[idx] = ew[e]; }
        int old = atomicCAS(&w.slot[r], -1, -3);
        if (old == -1) w.deg[r] = 1.0f;
      }
    }
  }
  for (long e = 4L * nv + g; e < E; e += gs) {
    int c = w.wscol[e];
    int s = w.slot[c];
    if (s >= 0) {
      int r = is64 ? (int)ell[e] : eiraw[e];
      int idx = atomicAdd(&w.cnt[2], 1);
      if (idx < L2CAP) { w.l2r[idx] = r; w.l2s[idx] = s; w.l2w[idx] = ew[e]; }
      int old = atomicCAS(&w.slot[r], -1, -3);
      if (old == -1) w.deg[r] = 1.0f;
    }
  }
}

// K4: deg accumulation for marked nodes only (~5K atomics)
__global__ void kpassC(WsPtrs w, const float* ew, int E) {
  int g = blockIdx.x * blockDim.x + threadIdx.x;
  int gs = gridDim.x * blockDim.x;
  const int4* c4 = (const int4*)w.wscol;
  int nv = E >> 2;
  for (int j = g; j < nv; j += gs) {
    int4 v = c4[j];
    #pragma unroll
    for (int t = 0; t < 4; ++t) {
      int c = (t == 0) ? v.x : (t == 1) ? v.y : (t == 2) ? v.z : v.w;
      if (w.slot[c] != -1) atomicAdd(&w.deg[c], ew[4L * j + t]);
    }
  }
  for (long e = 4L * nv + g; e < E; e += gs) {
    int c = w.wscol[e];
    if (w.slot[c] != -1) atomicAdd(&w.deg[c], ew[e]);
  }
}

// device-scope join: every block signals exactly once, then polls.
__device__ __forceinline__ void join(int* ctr, int tid) {
  __threadfence();
  __syncthreads();
  if (tid == 0) {
    __hip_atomic_fetch_add(ctr, 1, __ATOMIC_RELEASE, __HIP_MEMORY_SCOPE_AGENT);
    while (__hip_atomic_load(ctr, __ATOMIC_ACQUIRE, __HIP_MEMORY_SCOPE_AGENT) < NTB)
      __builtin_amdgcn_s_sleep(4);
  }
  __syncthreads();
}

// K5: 32 blocks x 256 threads; 3 spin-joins; all weight streams parallel across CUs.
__global__ void __launch_bounds__(256) ktail(
    WsPtrs w, const float* x, const float* W1, const float* b1,
    const float* W2, const float* b2, const float* mask,
    const float* Wh1, const float* bh1,
    const float* Wh2, const float* bh2,
    const float* Wh3, const float* bh3, float* out) {
  __shared__ float xs[2][INDIM];
  __shared__ int   l1rS[L1CAP];
  __shared__ float l1wS[L1CAP];
  __shared__ float buf[256];
  __shared__ float pp[256];
  __shared__ float f1L[16];
  int tid = threadIdx.x, bid = blockIdx.x;
  int tgt = w.cnt[4];
  int ns = w.cnt[1]; if (ns > SCAP) ns = SCAP;
  int n1 = w.cnt[0]; if (n1 > L1CAP) n1 = L1CAP;
  int n2 = w.cnt[2]; if (n2 > L2CAP) n2 = L2CAP;
  float dti = rsqrtf(w.deg[tgt]);
  for (int i = tid; i < n1; i += 256) { l1rS[i] = w.l1r[i]; l1wS[i] = w.l1w[i]; }

  // ---- stage 0: slot-parallel xsum -> W1 matvec -> a_v*relu -> h2 atomics
  int grp = tid >> 7, lane = tid & 127;
  for (int s = bid; s < ns; s += NTB) {
    int v = w.s1[s];
    float dv = w.deg[v], dvi = rsqrtf(dv);
    ((float*)xs)[tid] = 0.f;            // 2*128 == 256 threads
    __syncthreads();                    // also covers l1 preload (first iter)
    for (int i = grp; i < n2; i += 2) { // 2 lane-groups split the edge list
      if (w.l2s[i] == s) {
        int r = w.l2r[i];
        float nrm = rsqrtf(w.deg[r]) * w.l2w[i] * dvi;
        xs[grp][lane] += nrm * x[(long)r * INDIM + lane];
      }
    }
    __syncthreads();
    float h = b1[tid];
    #pragma unroll 8
    for (int k = 0; k < INDIM; ++k) h += (xs[0][k] + xs[1][k]) * W1[k * HID + tid];
    float wsum = 0.f;                   // sum of l1 weights with row==v
    for (int i = 0; i < n1; ++i) if (l1rS[i] == v) wsum += l1wS[i];
    atomicAdd(&w.h2[tid], dvi * wsum * dti * fmaxf(h, 0.f));
    __syncthreads();                    // protect xs for next slot
  }
  join(&w.cnt[8], tid);

  // ---- stage A: z = relu(h2 @ W2 + b2) * mask[tgt]; 16 blocks x 16 outputs
  if (bid < 16) {
    buf[tid] = __hip_atomic_load(&w.h2[tid], __ATOMIC_RELAXED,
                                 __HIP_MEMORY_SCOPE_AGENT);
    __syncthreads();
    int o0 = bid * 16, o = o0 + (tid & 15), ks = tid >> 4;
    float v = 0.f;
    #pragma unroll 4
    for (int k = ks * 16; k < ks * 16 + 16; ++k) v += buf[k] * W2[k * HID + o];
    pp[tid] = v;
    __syncthreads();
    if (tid < 16) {
      float zz = b2[o0 + tid];
      for (int s2 = 0; s2 < 16; ++s2) zz += pp[s2 * 16 + tid];
      w.z[o0 + tid] = fmaxf(zz, 0.f) * mask[tgt];
    }
  }
  join(&w.cnt[9], tid);

  // ---- stage B: f1 slice (16 outs/block) + f2pre atomic contributions
  buf[tid] = __hip_atomic_load(&w.z[tid], __ATOMIC_RELAXED,
                               __HIP_MEMORY_SCOPE_AGENT);
  __syncthreads();
  {
    int o0 = bid * 16, o = o0 + (tid & 15), ks = tid >> 4;
    float v = 0.f;
    #pragma unroll 4
    for (int k = ks * 16; k < ks * 16 + 16; ++k) v += buf[k] * Wh1[k * 512 + o];
    pp[tid] = v;
    __syncthreads();
    if (tid < 16) {
      float v2 = w.C[o0 + tid] + bh1[o0 + tid];
      for (int s2 = 0; s2 < 16; ++s2) v2 += pp[s2 * 16 + tid];
      f1L[tid] = fmaxf(v2, 0.f);
    }
    __syncthreads();
    if (tid < 128) {
      float v3 = 0.f;
      #pragma unroll
      for (int j = 0; j < 16; ++j) v3 += f1L[j] * Wh2[(o0 + j) * 128 + tid];
      atomicAdd(&w.f2pre[tid], v3);
    }
  }
  // signal done2; only block 0 continues
  __threadfence();
  __syncthreads();
  if (tid == 0)
    __hip_atomic_fetch_add(&w.cnt[10], 1, __ATOMIC_RELEASE, __HIP_MEMORY_SCOPE_AGENT);
  if (bid != 0) return;
  if (tid == 0)
    while (__hip_atomic_load(&w.cnt[10], __ATOMIC_ACQUIRE,
                             __HIP_MEMORY_SCOPE_AGENT) < NTB)
      __builtin_amdgcn_s_sleep(4);
  __syncthreads();

  // ---- stage C: out = bh3 + sum relu(f2pre+bh2)*Wh3
  if (tid < 128)
    pp[tid] = fmaxf(__hip_atomic_load(&w.f2pre[tid], __ATOMIC_RELAXED,
                                      __HIP_MEMORY_SCOPE_AGENT) + bh2[tid], 0.f)
              * Wh3[tid];
  __syncthreads();
  if (tid == 0) {
    float s = bh3[0];
    for (int k = 0; k < 128; ++k) s += pp[k];
    out[0] = s;
  }
}

extern "C" void kernel_launch(void* const* d_in, const int* in_sizes, int n_in,
                              void* d_out, int out_size, void* d_ws, size_t ws_size,
                              hipStream_t stream) {
  const float* x    = (const float*)d_in[0];
  const int*   ei   = (const int*)d_in[1];
  const float* ew   = (const float*)d_in[2];
  const float* mask = (const float*)d_in[3];
  const int*   wtI  = (const int*)d_in[4];
  const int*   mutI = (const int*)d_in[5];
  const float* W1   = (const float*)d_in[6];
  const float* b1   = (const float*)d_in[7];
  const float* W2   = (const float*)d_in[8];
  const float* b2   = (const float*)d_in[9];
  const float* aa   = (const float*)d_in[10];
  const float* pemb = (const float*)d_in[11];
  const float* Wh1  = (const float*)d_in[12];
  const float* bh1  = (const float*)d_in[13];
  const float* Wh2  = (const float*)d_in[14];
  const float* bh2  = (const float*)d_in[15];
  const float* Wh3  = (const float*)d_in[16];
  const float* bh3  = (const float*)d_in[17];
  float* out = (float*)d_out;
  const int N = in_sizes[3];   // mut_mask length
  const int E = in_sizes[2];   // edge_weight length

  char* q = (char*)d_ws;
  auto take = [&](size_t bytes) -> char* {
    char* r = q; q += (bytes + 255) & ~(size_t)255; return r;
  };
  WsPtrs w;
  w.cnt   = (int*)take(64);
  w.deg   = (float*)take((size_t)N * 4);
  w.slot  = (int*)take((size_t)N * 4);
  w.s1    = (int*)take(SCAP * 4);
  w.l1r   = (int*)take(L1CAP * 4);
  w.l1w   = (float*)take(L1CAP * 4);
  w.l2r   = (int*)take(L2CAP * 4);
  w.l2s   = (int*)take(L2CAP * 4);
  w.l2w   = (float*)take(L2CAP * 4);
  w.wscol = (int*)take((size_t)E * 4);
  w.h2    = (float*)take(HID * 4);
  w.C     = (float*)take(512 * 4);
  w.z     = (float*)take(256 * 4);
  w.f2pre = (float*)take(128 * 4);

  kinit  <<<512, 256, 0, stream>>>(w, ei, mask, N, E);
  kpassA <<<NSCAN + 8, 256, 0, stream>>>(w, ei, ew, wtI, mutI, aa, pemb, Wh1, E);
  kpassB <<<1024, 256, 0, stream>>>(w, ei, ew, E);
  kpassC <<<1024, 256, 0, stream>>>(w, ew, E);
  ktail  <<<NTB, 256, 0, stream>>>(w, x, W1, b1, W2, b2, mask,
                                   Wh1, bh1, Wh2, bh2, Wh3, bh3, out);
}